// Round 1
// baseline (432.661 us; speedup 1.0000x reference)
//
#include <hip/hip_runtime.h>
#include <hip/hip_fp16.h>

#define NN 512

union U4H8 {
    uint4 u;
    __half2 h2[4];
};

__device__ __forceinline__ float wave_reduce_sum(float v) {
    #pragma unroll
    for (int off = 32; off > 0; off >>= 1)
        v += __shfl_xor(v, off, 64);
    return v;
}

// Load 8 consecutive elements of E (either fp16 workspace or exp of fp32 input).
template<bool USE_E>
__device__ __forceinline__ void load8(const __half* __restrict__ E,
                                      const float* __restrict__ S,
                                      int idx, float e[8]) {
    if constexpr (USE_E) {
        U4H8 u;
        u.u = *reinterpret_cast<const uint4*>(E + idx);
        #pragma unroll
        for (int k = 0; k < 4; ++k) {
            float2 f = __half22float2(u.h2[k]);
            e[2 * k]     = f.x;
            e[2 * k + 1] = f.y;
        }
    } else {
        const float4* p = reinterpret_cast<const float4*>(S + idx);
        float4 x0 = p[0];
        float4 x1 = p[1];
        e[0] = __expf(x0.x); e[1] = __expf(x0.y);
        e[2] = __expf(x0.z); e[3] = __expf(x0.w);
        e[4] = __expf(x1.x); e[5] = __expf(x1.y);
        e[6] = __expf(x1.z); e[7] = __expf(x1.w);
    }
}

template<bool USE_E>
__global__ __launch_bounds__(1024)
void sinkhorn_kernel(const float* __restrict__ Sg,
                     __half* __restrict__ Eg,
                     float* __restrict__ outg) {
    const int mat = blockIdx.x;
    const size_t base = (size_t)mat * NN * NN;
    const float* S = Sg + base;
    __half* E = USE_E ? (Eg + base) : nullptr;
    float* out = outg + base;

    __shared__ float Av[NN];
    __shared__ float Bv[NN];
    __shared__ float part[16][NN];

    const int tid  = threadIdx.x;
    const int lane = tid & 63;
    const int w    = tid >> 6;   // wave id 0..15

    // ---- pass 0: E = exp(S); row sums with B = 1  -> A (first row normalize) ----
    #pragma unroll 2
    for (int rr = 0; rr < 32; ++rr) {
        const int row = w * 32 + rr;
        const int idx = row * NN + lane * 8;
        const float4* p = reinterpret_cast<const float4*>(S + idx);
        float4 x0 = p[0];
        float4 x1 = p[1];
        float e[8];
        e[0] = __expf(x0.x); e[1] = __expf(x0.y);
        e[2] = __expf(x0.z); e[3] = __expf(x0.w);
        e[4] = __expf(x1.x); e[5] = __expf(x1.y);
        e[6] = __expf(x1.z); e[7] = __expf(x1.w);
        if constexpr (USE_E) {
            U4H8 u;
            #pragma unroll
            for (int k = 0; k < 4; ++k) {
                __half2 h;
                h.x = __float2half_rn(e[2 * k]);
                h.y = __float2half_rn(e[2 * k + 1]);
                u.h2[k] = h;
            }
            *reinterpret_cast<uint4*>(E + idx) = u.u;
        }
        float acc = ((e[0] + e[1]) + (e[2] + e[3])) + ((e[4] + e[5]) + (e[6] + e[7]));
        acc = wave_reduce_sum(acc);
        if (lane == 0) Av[row] = 1.0f / acc;
    }
    __syncthreads();

    for (int it = 0; it < 10; ++it) {
        // ---- col pass: B_j = 1 / sum_i E_ij * A_i ----
        {
            float c[8] = {0.f, 0.f, 0.f, 0.f, 0.f, 0.f, 0.f, 0.f};
            const int jg = lane;   // 64 column groups of 8
            const int rg = w;      // 16 row groups of 32
            #pragma unroll 4
            for (int ii = 0; ii < 32; ++ii) {
                const int i = rg * 32 + ii;
                const float a = Av[i];          // wave-uniform broadcast
                float e[8];
                load8<USE_E>(E, S, i * NN + jg * 8, e);
                #pragma unroll
                for (int k = 0; k < 8; ++k) c[k] += e[k] * a;
            }
            *reinterpret_cast<float4*>(&part[rg][jg * 8])     = make_float4(c[0], c[1], c[2], c[3]);
            *reinterpret_cast<float4*>(&part[rg][jg * 8 + 4]) = make_float4(c[4], c[5], c[6], c[7]);
            __syncthreads();
            if (tid < NN) {
                float s = 0.f;
                #pragma unroll
                for (int k = 0; k < 16; ++k) s += part[k][tid];
                Bv[tid] = 1.0f / s;
            }
            __syncthreads();
        }

        // ---- row pass: A_i = 1 / sum_j E_ij * B_j (not needed after last col pass) ----
        if (it < 9) {
            float b[8];
            #pragma unroll
            for (int k = 0; k < 8; ++k) b[k] = Bv[lane * 8 + k];
            #pragma unroll 2
            for (int rr = 0; rr < 32; ++rr) {
                const int row = w * 32 + rr;
                float e[8];
                load8<USE_E>(E, S, row * NN + lane * 8, e);
                float acc = 0.f;
                #pragma unroll
                for (int k = 0; k < 8; ++k) acc += e[k] * b[k];
                acc = wave_reduce_sum(acc);
                if (lane == 0) Av[row] = 1.0f / acc;
            }
            __syncthreads();
        }
    }

    // ---- final pass: out_ij = E_ij * A_i * B_j ----
    {
        float b[8];
        #pragma unroll
        for (int k = 0; k < 8; ++k) b[k] = Bv[lane * 8 + k];
        #pragma unroll 2
        for (int rr = 0; rr < 32; ++rr) {
            const int row = w * 32 + rr;
            const float a = Av[row];
            float e[8];
            load8<USE_E>(E, S, row * NN + lane * 8, e);
            float o[8];
            #pragma unroll
            for (int k = 0; k < 8; ++k) o[k] = e[k] * a * b[k];
            float* op = out + row * NN + lane * 8;
            *reinterpret_cast<float4*>(op)     = make_float4(o[0], o[1], o[2], o[3]);
            *reinterpret_cast<float4*>(op + 4) = make_float4(o[4], o[5], o[6], o[7]);
        }
    }
}

extern "C" void kernel_launch(void* const* d_in, const int* in_sizes, int n_in,
                              void* d_out, int out_size, void* d_ws, size_t ws_size,
                              hipStream_t stream) {
    const float* S = reinterpret_cast<const float*>(d_in[0]);
    float* out = reinterpret_cast<float*>(d_out);
    const int nmat = in_sizes[0] / (NN * NN);   // 128 for (8,16,512,512)
    const size_t e_bytes = (size_t)in_sizes[0] * sizeof(__half);

    if (d_ws != nullptr && ws_size >= e_bytes) {
        sinkhorn_kernel<true><<<dim3(nmat), dim3(1024), 0, stream>>>(
            S, reinterpret_cast<__half*>(d_ws), out);
    } else {
        sinkhorn_kernel<false><<<dim3(nmat), dim3(1024), 0, stream>>>(
            S, nullptr, out);
    }
}